// Round 4
// baseline (559.022 us; speedup 1.0000x reference)
//
#include <hip/hip_runtime.h>

// MHA: B=4, S=2048, D=1024, H=16, Dh=64.  M = B*S = 8192.
// bf16 MFMA 16x16x32 (verified layouts):
//   C/D: col = lane&15, row = (lane>>4)*4 + reg
//   A  : A[m = lane&15][k = (lane>>4)*8 + j]
//   B  : B[k = (lane>>4)*8 + j][n = lane&15]
// Flash v4: ZERO barriers. K/V fragments loaded straight from global into
// MFMA layout (all 4 waves load identical addresses -> L1 reuse). LDS only
// for the wave-private P C-layout->A-layout roundtrip. l-sum computed by an
// extra MFMA against a ones B-fragment (lands in PV output layout directly).

typedef short bf16x8 __attribute__((ext_vector_type(8)));
typedef short bf16x4 __attribute__((ext_vector_type(4)));
typedef float f32x4 __attribute__((ext_vector_type(4)));

__device__ __forceinline__ short f2bf(float x) {  // RNE
    union { float f; unsigned int u; } un; un.f = x;
    unsigned int u = un.u;
    return (short)(unsigned short)((u + 0x7fffu + ((u >> 16) & 1u)) >> 16);
}

__device__ __forceinline__ void gll16(const void* g, void* l) {
    __builtin_amdgcn_global_load_lds(
        (const __attribute__((address_space(1))) void*)g,
        (__attribute__((address_space(3))) void*)l, 16, 0, 0);
}

// ---- fused fp32 -> bf16 convert ----
struct CvtArgs { const float* s[4]; unsigned short* d[4]; int n4; };
__global__ __launch_bounds__(256) void cvt_bf16(CvtArgs ca) {
    const float* s = ca.s[blockIdx.y];
    unsigned short* d = ca.d[blockIdx.y];
    int i = blockIdx.x * blockDim.x + threadIdx.x;
    int stride = gridDim.x * blockDim.x;
    const float4* s4 = reinterpret_cast<const float4*>(s);
    bf16x4* d4 = reinterpret_cast<bf16x4*>(d);
    for (; i < ca.n4; i += stride) {
        float4 x = s4[i];
        bf16x4 y;
        y[0] = f2bf(x.x); y[1] = f2bf(x.y); y[2] = f2bf(x.z); y[3] = f2bf(x.w);
        d4[i] = y;
    }
}

// ---- GEMM core: C[8192][1024] = A @ W^T, val = (acc+bias)*scale ----
// mode 0: fp32 [M][N] ; mode 1: bf16 [b*16+h][s][d] ; mode 2: bf16 [b*16+h][d][s]
__device__ __forceinline__ void gemm_core(const unsigned short* __restrict__ A,
                                          const unsigned short* __restrict__ W,
                                          const float* __restrict__ bias,
                                          float scale, void* __restrict__ out,
                                          int mode) {
    __shared__ unsigned short As[128 * 64];  // 128 rows x 128B, source-swizzled
    __shared__ unsigned short Bs[128 * 64];
    const int tid = threadIdx.x;
    const int m0 = blockIdx.y * 128, n0 = blockIdx.x * 128;
    const int wave = tid >> 6, lane = tid & 63;
    const int wm = (wave >> 1) * 64, wn = (wave & 1) * 64;
    const int l15 = lane & 15, quad = lane >> 4;
    const int srow = tid >> 3;
    const int scol = ((tid & 7) ^ (srow & 7)) * 8;
    const int cb = (l15 & 7);

    f32x4 acc[4][4] = {};

    for (int k0 = 0; k0 < 1024; k0 += 64) {
        __syncthreads();
#pragma unroll
        for (int ro = 0; ro < 4; ++ro) {
            gll16(&A[(size_t)(m0 + ro * 32 + srow) * 1024 + k0 + scol], &As[ro * 2048 + tid * 8]);
            gll16(&W[(size_t)(n0 + ro * 32 + srow) * 1024 + k0 + scol], &Bs[ro * 2048 + tid * 8]);
        }
        __syncthreads();
#pragma unroll
        for (int kk = 0; kk < 2; ++kk) {
            const int co = ((4 * kk + quad) ^ cb) * 8;
            bf16x8 a[4], b[4];
#pragma unroll
            for (int i = 0; i < 4; ++i)
                a[i] = *reinterpret_cast<bf16x8*>(&As[(wm + i * 16 + l15) * 64 + co]);
#pragma unroll
            for (int j = 0; j < 4; ++j)
                b[j] = *reinterpret_cast<bf16x8*>(&Bs[(wn + j * 16 + l15) * 64 + co]);
#pragma unroll
            for (int i = 0; i < 4; ++i)
#pragma unroll
                for (int j = 0; j < 4; ++j)
                    acc[i][j] = __builtin_amdgcn_mfma_f32_16x16x32_bf16(a[i], b[j], acc[i][j], 0, 0, 0);
        }
    }

#pragma unroll
    for (int i = 0; i < 4; ++i) {
#pragma unroll
        for (int j = 0; j < 4; ++j) {
#pragma unroll
            for (int r = 0; r < 4; ++r) {
                int m = m0 + wm + i * 16 + quad * 4 + r;
                int n = n0 + wn + j * 16 + l15;
                float val = (acc[i][j][r] + bias[n]) * scale;
                if (mode == 0) {
                    reinterpret_cast<float*>(out)[(size_t)m * 1024 + n] = val;
                } else {
                    int b_ = m >> 11, s = m & 2047, h = n >> 6, d = n & 63;
                    size_t off = (mode == 1)
                                     ? ((size_t)((b_ * 16 + h) * 2048 + s) * 64 + d)
                                     : ((size_t)((b_ * 16 + h) * 64 + d) * 2048 + s);
                    reinterpret_cast<unsigned short*>(out)[off] = (unsigned short)f2bf(val);
                }
            }
        }
    }
}

struct QkvArgs {
    const unsigned short* A[3];
    const unsigned short* W[3];
    const float* bias[3];
    float scale[3];
    unsigned short* out[3];
    int mode[3];
};
__global__ __launch_bounds__(256) void gemm_qkv(QkvArgs ga) {
    int z = blockIdx.z;
    gemm_core(ga.A[z], ga.W[z], ga.bias[z], ga.scale[z], ga.out[z], ga.mode[z]);
}

__global__ __launch_bounds__(256) void gemm_wo(const unsigned short* __restrict__ A,
                                               const unsigned short* __restrict__ W,
                                               const float* __restrict__ bias,
                                               float* __restrict__ out) {
    gemm_core(A, W, bias, 1.0f, out, 0);
}

// ---- Flash v4: barrier-free ----
// Qh,Kh: [64][2048][64]; Vt: [64][64][2048]; Oa: [8192][1024] bf16.
// Q pre-scaled by 0.125*log2(e) -> exp2 directly. Block = (bh, 128 q), 4 waves.
__global__ __launch_bounds__(256) void flash_attn(const unsigned short* __restrict__ Qh,
                                                  const unsigned short* __restrict__ Kh,
                                                  const unsigned short* __restrict__ Vt,
                                                  unsigned short* __restrict__ Oa) {
    constexpr int LD = 72;  // P row stride (elems); 144B rows
    __shared__ unsigned short Ps[4 * 32 * LD];  // wave-private 32x64 P tiles
    const int tid = threadIdx.x;
    const int bh = blockIdx.y;
    const int q0 = blockIdx.x * 128;
    const unsigned short* Qb = Qh + (size_t)bh * 2048 * 64;
    const unsigned short* Kb = Kh + (size_t)bh * 2048 * 64;
    const unsigned short* Vb = Vt + (size_t)bh * 64 * 2048;
    const int wave = tid >> 6, lane = tid & 63;
    const int l15 = lane & 15, quad = lane >> 4;
    const int wq = wave * 32;
    unsigned short* Pw = &Ps[wave * 32 * LD];

    // Q fragments (B-operand of S^T = K·Q^T): loop-invariant registers.
    bf16x8 qreg[2][2];
#pragma unroll
    for (int i = 0; i < 2; ++i)
#pragma unroll
        for (int kk = 0; kk < 2; ++kk)
            qreg[i][kk] = *reinterpret_cast<const bf16x8*>(
                &Qb[(size_t)(q0 + wq + i * 16 + l15) * 64 + kk * 32 + quad * 8]);

    bf16x8 ones;
#pragma unroll
    for (int j = 0; j < 8; ++j) ones[j] = (short)0x3F80;  // bf16 1.0

    f32x4 o[2][4] = {};
    f32x4 lacc[2] = {};

    for (int kv0 = 0; kv0 < 2048; kv0 += 64) {
        // V B-fragments: Vt row (n*16+l15), contiguous along kv. Issue early.
        bf16x8 bv[2][4];
#pragma unroll
        for (int kk = 0; kk < 2; ++kk)
#pragma unroll
            for (int n = 0; n < 4; ++n)
                bv[kk][n] = *reinterpret_cast<const bf16x8*>(
                    &Vb[(size_t)(n * 16 + l15) * 2048 + kv0 + kk * 32 + quad * 8]);

        // S^T[kv][q] = K·Q^T ; K A-fragments straight from global.
        f32x4 sacc[2][4] = {};
#pragma unroll
        for (int kk = 0; kk < 2; ++kk) {
            bf16x8 ak[4];
#pragma unroll
            for (int j = 0; j < 4; ++j)
                ak[j] = *reinterpret_cast<const bf16x8*>(
                    &Kb[(size_t)(kv0 + j * 16 + l15) * 64 + kk * 32 + quad * 8]);
#pragma unroll
            for (int i = 0; i < 2; ++i)
#pragma unroll
                for (int j = 0; j < 4; ++j)
                    sacc[i][j] = __builtin_amdgcn_mfma_f32_16x16x32_bf16(ak[j], qreg[i][kk], sacc[i][j], 0, 0, 0);
        }

        // p = exp2(s); pack pairs (+0x8000 round) and store to wave-private P.
#pragma unroll
        for (int i = 0; i < 2; ++i) {
#pragma unroll
            for (int j = 0; j < 4; ++j) {
                float p0 = __builtin_amdgcn_exp2f(sacc[i][j][0]);
                float p1 = __builtin_amdgcn_exp2f(sacc[i][j][1]);
                float p2 = __builtin_amdgcn_exp2f(sacc[i][j][2]);
                float p3 = __builtin_amdgcn_exp2f(sacc[i][j][3]);
                union { float f; unsigned u; } a0{p0}, a1{p1}, a2{p2}, a3{p3};
                unsigned lo = __builtin_amdgcn_perm(a1.u + 0x8000u, a0.u + 0x8000u, 0x07060302u);
                unsigned hi = __builtin_amdgcn_perm(a3.u + 0x8000u, a2.u + 0x8000u, 0x07060302u);
                uint2 pk; pk.x = lo; pk.y = hi;
                *reinterpret_cast<uint2*>(&Pw[(i * 16 + l15) * LD + j * 16 + quad * 4]) = pk;
            }
        }

        // O += P·V ; l += P·ones (l lands in PV C-layout: row = q).
#pragma unroll
        for (int kk = 0; kk < 2; ++kk) {
            bf16x8 ap[2];
#pragma unroll
            for (int i = 0; i < 2; ++i)
                ap[i] = *reinterpret_cast<bf16x8*>(&Pw[(i * 16 + l15) * LD + kk * 32 + quad * 8]);
#pragma unroll
            for (int i = 0; i < 2; ++i)
                lacc[i] = __builtin_amdgcn_mfma_f32_16x16x32_bf16(ap[i], ones, lacc[i], 0, 0, 0);
#pragma unroll
            for (int n = 0; n < 4; ++n) {
#pragma unroll
                for (int i = 0; i < 2; ++i)
                    o[i][n] = __builtin_amdgcn_mfma_f32_16x16x32_bf16(ap[i], bv[kk][n], o[i][n], 0, 0, 0);
            }
        }
    }

    // epilogue: rinv from lacc (already in o's row layout), store bf16 token layout
    const int b_ = bh >> 4, h = bh & 15;
#pragma unroll
    for (int i = 0; i < 2; ++i) {
        f32x4 rv;
#pragma unroll
        for (int r = 0; r < 4; ++r) rv[r] = 1.0f / lacc[i][r];
#pragma unroll
        for (int n = 0; n < 4; ++n)
#pragma unroll
            for (int r = 0; r < 4; ++r) {
                int s = q0 + wq + i * 16 + quad * 4 + r;
                int d = n * 16 + l15;
                Oa[(size_t)(b_ * 2048 + s) * 1024 + h * 64 + d] =
                    (unsigned short)f2bf(o[i][n][r] * rv[r]);
            }
    }
}

extern "C" void kernel_launch(void* const* d_in, const int* in_sizes, int n_in,
                              void* d_out, int out_size, void* d_ws, size_t ws_size,
                              hipStream_t stream) {
    const float* q  = (const float*)d_in[0];
    const float* k  = (const float*)d_in[1];
    const float* v  = (const float*)d_in[2];
    const float* Wq = (const float*)d_in[3];
    const float* bq = (const float*)d_in[4];
    const float* Wk = (const float*)d_in[5];
    const float* bk = (const float*)d_in[6];
    const float* Wv = (const float*)d_in[7];
    const float* bv = (const float*)d_in[8];
    const float* Wo = (const float*)d_in[9];
    const float* bo = (const float*)d_in[10];

    const size_t E = (size_t)8192 * 1024;
    const size_t WE = (size_t)1024 * 1024;
    // aliasing (sequential dependency chain): r0=q_bf->Kh ; r1=k_bf->Vt ; r2=v_bf->Ao ; r3=Qh
    unsigned short* r0 = (unsigned short*)d_ws;
    unsigned short* r1 = r0 + E;
    unsigned short* r2 = r1 + E;
    unsigned short* r3 = r2 + E;
    unsigned short* wqb = r3 + E;
    unsigned short* wkb = wqb + WE;
    unsigned short* wvb = wkb + WE;
    unsigned short* wob = wvb + WE;

    CvtArgs ca;
    ca.s[0] = q; ca.d[0] = r0;
    ca.s[1] = k; ca.d[1] = r1;
    ca.s[2] = v; ca.d[2] = r2;
    ca.s[3] = q; ca.d[3] = r0;  // unused (grid.y = 3)
    ca.n4 = (int)(E / 4);
    cvt_bf16<<<dim3(1024, 3), 256, 0, stream>>>(ca);

    CvtArgs cw;
    cw.s[0] = Wq; cw.d[0] = wqb;
    cw.s[1] = Wk; cw.d[1] = wkb;
    cw.s[2] = Wv; cw.d[2] = wvb;
    cw.s[3] = Wo; cw.d[3] = wob;
    cw.n4 = (int)(WE / 4);
    cvt_bf16<<<dim3(256, 4), 256, 0, stream>>>(cw);

    const float QSCALE = 0.125f * 1.44269504088896340736f;  // fold log2(e) for exp2

    QkvArgs ga;
    ga.A[0] = r0; ga.W[0] = wqb; ga.bias[0] = bq; ga.scale[0] = QSCALE; ga.out[0] = r3; ga.mode[0] = 1;
    ga.A[1] = r1; ga.W[1] = wkb; ga.bias[1] = bk; ga.scale[1] = 1.0f;   ga.out[1] = r0; ga.mode[1] = 1;
    ga.A[2] = r2; ga.W[2] = wvb; ga.bias[2] = bv; ga.scale[2] = 1.0f;   ga.out[2] = r1; ga.mode[2] = 2;
    gemm_qkv<<<dim3(8, 64, 3), 256, 0, stream>>>(ga);

    flash_attn<<<dim3(16, 64), 256, 0, stream>>>(r3, r0, r1, r2);  // Ao = r2
    gemm_wo<<<dim3(8, 64), 256, 0, stream>>>(r2, wob, bo, (float*)d_out);
}

// Round 5
// 374.115 us; speedup vs baseline: 1.4943x; 1.4943x over previous
//
#include <hip/hip_runtime.h>

// MHA: B=4, S=2048, D=1024, H=16, Dh=64.  M = B*S = 8192.
// bf16 MFMA 16x16x32 (verified layouts):
//   C/D: col = lane&15, row = (lane>>4)*4 + reg
//   A  : A[m = lane&15][k = (lane>>4)*8 + j]
//   B  : B[k = (lane>>4)*8 + j][n = lane&15]
// Flash v5: LDS-staged K/V (global_load_lds 16B + XOR-chunk swizzle), PING-PONG
// double buffer -> ONE barrier/iter with a warm vmcnt drain. P roundtrips
// through wave-private LDS (no barrier). l-sum via MFMA against a ones
// B-fragment (lands in PV C-layout; no VALU adds, no epilogue shuffles).
// R4 lesson: direct global->register fragments serialize on load latency
// under VGPR pressure; LDS DMA staging decouples it.

typedef short bf16x8 __attribute__((ext_vector_type(8)));
typedef short bf16x4 __attribute__((ext_vector_type(4)));
typedef float f32x4 __attribute__((ext_vector_type(4)));

__device__ __forceinline__ short f2bf(float x) {  // RNE
    union { float f; unsigned int u; } un; un.f = x;
    unsigned int u = un.u;
    return (short)(unsigned short)((u + 0x7fffu + ((u >> 16) & 1u)) >> 16);
}

__device__ __forceinline__ void gll16(const void* g, void* l) {
    __builtin_amdgcn_global_load_lds(
        (const __attribute__((address_space(1))) void*)g,
        (__attribute__((address_space(3))) void*)l, 16, 0, 0);
}

// ---- fused fp32 -> bf16 convert ----
struct CvtArgs { const float* s[4]; unsigned short* d[4]; int n4; };
__global__ __launch_bounds__(256) void cvt_bf16(CvtArgs ca) {
    const float* s = ca.s[blockIdx.y];
    unsigned short* d = ca.d[blockIdx.y];
    int i = blockIdx.x * blockDim.x + threadIdx.x;
    int stride = gridDim.x * blockDim.x;
    const float4* s4 = reinterpret_cast<const float4*>(s);
    bf16x4* d4 = reinterpret_cast<bf16x4*>(d);
    for (; i < ca.n4; i += stride) {
        float4 x = s4[i];
        bf16x4 y;
        y[0] = f2bf(x.x); y[1] = f2bf(x.y); y[2] = f2bf(x.z); y[3] = f2bf(x.w);
        d4[i] = y;
    }
}

// ---- GEMM core: C[8192][1024] = A @ W^T, val = (acc+bias)*scale ----
// mode 0: fp32 [M][N] ; mode 1: bf16 [b*16+h][s][d] ; mode 2: bf16 [b*16+h][d][s]
__device__ __forceinline__ void gemm_core(const unsigned short* __restrict__ A,
                                          const unsigned short* __restrict__ W,
                                          const float* __restrict__ bias,
                                          float scale, void* __restrict__ out,
                                          int mode) {
    __shared__ unsigned short As[128 * 64];  // 128 rows x 128B, source-swizzled
    __shared__ unsigned short Bs[128 * 64];
    const int tid = threadIdx.x;
    const int m0 = blockIdx.y * 128, n0 = blockIdx.x * 128;
    const int wave = tid >> 6, lane = tid & 63;
    const int wm = (wave >> 1) * 64, wn = (wave & 1) * 64;
    const int l15 = lane & 15, quad = lane >> 4;
    const int srow = tid >> 3;
    const int scol = ((tid & 7) ^ (srow & 7)) * 8;
    const int cb = (l15 & 7);

    f32x4 acc[4][4] = {};

    for (int k0 = 0; k0 < 1024; k0 += 64) {
        __syncthreads();
#pragma unroll
        for (int ro = 0; ro < 4; ++ro) {
            gll16(&A[(size_t)(m0 + ro * 32 + srow) * 1024 + k0 + scol], &As[ro * 2048 + tid * 8]);
            gll16(&W[(size_t)(n0 + ro * 32 + srow) * 1024 + k0 + scol], &Bs[ro * 2048 + tid * 8]);
        }
        __syncthreads();
#pragma unroll
        for (int kk = 0; kk < 2; ++kk) {
            const int co = ((4 * kk + quad) ^ cb) * 8;
            bf16x8 a[4], b[4];
#pragma unroll
            for (int i = 0; i < 4; ++i)
                a[i] = *reinterpret_cast<bf16x8*>(&As[(wm + i * 16 + l15) * 64 + co]);
#pragma unroll
            for (int j = 0; j < 4; ++j)
                b[j] = *reinterpret_cast<bf16x8*>(&Bs[(wn + j * 16 + l15) * 64 + co]);
#pragma unroll
            for (int i = 0; i < 4; ++i)
#pragma unroll
                for (int j = 0; j < 4; ++j)
                    acc[i][j] = __builtin_amdgcn_mfma_f32_16x16x32_bf16(a[i], b[j], acc[i][j], 0, 0, 0);
        }
    }

#pragma unroll
    for (int i = 0; i < 4; ++i) {
#pragma unroll
        for (int j = 0; j < 4; ++j) {
#pragma unroll
            for (int r = 0; r < 4; ++r) {
                int m = m0 + wm + i * 16 + quad * 4 + r;
                int n = n0 + wn + j * 16 + l15;
                float val = (acc[i][j][r] + bias[n]) * scale;
                if (mode == 0) {
                    reinterpret_cast<float*>(out)[(size_t)m * 1024 + n] = val;
                } else {
                    int b_ = m >> 11, s = m & 2047, h = n >> 6, d = n & 63;
                    size_t off = (mode == 1)
                                     ? ((size_t)((b_ * 16 + h) * 2048 + s) * 64 + d)
                                     : ((size_t)((b_ * 16 + h) * 64 + d) * 2048 + s);
                    reinterpret_cast<unsigned short*>(out)[off] = (unsigned short)f2bf(val);
                }
            }
        }
    }
}

struct QkvArgs {
    const unsigned short* A[3];
    const unsigned short* W[3];
    const float* bias[3];
    float scale[3];
    unsigned short* out[3];
    int mode[3];
};
__global__ __launch_bounds__(256) void gemm_qkv(QkvArgs ga) {
    int z = blockIdx.z;
    gemm_core(ga.A[z], ga.W[z], ga.bias[z], ga.scale[z], ga.out[z], ga.mode[z]);
}

__global__ __launch_bounds__(256) void gemm_wo(const unsigned short* __restrict__ A,
                                               const unsigned short* __restrict__ W,
                                               const float* __restrict__ bias,
                                               float* __restrict__ out) {
    gemm_core(A, W, bias, 1.0f, out, 0);
}

// ---- Flash v5 ----
// Qh,Kh: [64][2048][64]; Vt: [64][64][2048]; Oa: [8192][1024] bf16.
// Q pre-scaled by 0.125*log2(e) -> exp2 directly. Block = (bh, 128 q), 4 waves.
__global__ __launch_bounds__(256, 3) void flash_attn(const unsigned short* __restrict__ Qh,
                                                     const unsigned short* __restrict__ Kh,
                                                     const unsigned short* __restrict__ Vt,
                                                     unsigned short* __restrict__ Oa) {
    constexpr int LD = 72;  // P row stride (elems); 144B rows
    __shared__ unsigned short Ks[2][64 * 64];   // ping-pong, source-swizzled
    __shared__ unsigned short Vs[2][64 * 64];   // V^T window [d][kv]
    __shared__ unsigned short Ps[4 * 32 * LD];  // wave-private 32x64 P tiles
    const int tid = threadIdx.x;
    const int bh = blockIdx.y;
    const int q0 = blockIdx.x * 128;
    const unsigned short* Qb = Qh + (size_t)bh * 2048 * 64;
    const unsigned short* Kb = Kh + (size_t)bh * 2048 * 64;
    const unsigned short* Vb = Vt + (size_t)bh * 64 * 2048;
    const int wave = tid >> 6, lane = tid & 63;
    const int l15 = lane & 15, quad = lane >> 4;
    const int wq = wave * 32;
    const int srow = tid >> 3;                       // 0..31 per round
    const int scol = ((tid & 7) ^ (srow & 7)) * 8;   // swizzled source chunk
    const int cb = (l15 & 7);
    unsigned short* Pw = &Ps[wave * 32 * LD];

    // Q fragments (B-operand of S^T = K·Q^T): loop-invariant registers.
    bf16x8 qreg[2][2];
#pragma unroll
    for (int i = 0; i < 2; ++i)
#pragma unroll
        for (int kk = 0; kk < 2; ++kk)
            qreg[i][kk] = *reinterpret_cast<const bf16x8*>(
                &Qb[(size_t)(q0 + wq + i * 16 + l15) * 64 + kk * 32 + quad * 8]);

    bf16x8 ones;
#pragma unroll
    for (int j = 0; j < 8; ++j) ones[j] = (short)0x3F80;  // bf16 1.0

    f32x4 o[2][4] = {};
    f32x4 lacc[2] = {};

    // prologue: stage tile 0
#pragma unroll
    for (int ro = 0; ro < 2; ++ro) {
        gll16(&Kb[(size_t)(ro * 32 + srow) * 64 + scol], &Ks[0][ro * 2048 + tid * 8]);
        gll16(&Vb[(size_t)(ro * 32 + srow) * 2048 + scol], &Vs[0][ro * 2048 + tid * 8]);
    }
    __syncthreads();

    for (int it = 0; it < 32; ++it) {
        const int buf = it & 1;
        if (it < 31) {  // prefetch tile it+1 into the other buffer (no barrier)
            int kvn = (it + 1) * 64;
#pragma unroll
            for (int ro = 0; ro < 2; ++ro) {
                gll16(&Kb[(size_t)(kvn + ro * 32 + srow) * 64 + scol], &Ks[buf ^ 1][ro * 2048 + tid * 8]);
                gll16(&Vb[(size_t)(ro * 32 + srow) * 2048 + kvn + scol], &Vs[buf ^ 1][ro * 2048 + tid * 8]);
            }
        }

        // S^T[kv][q] = K·Q^T ; wave owns q cols [wq, wq+32)
        f32x4 sacc[2][4] = {};
#pragma unroll
        for (int kk = 0; kk < 2; ++kk) {
            const int co = ((4 * kk + quad) ^ cb) * 8;
            bf16x8 ak[4];
#pragma unroll
            for (int j = 0; j < 4; ++j)
                ak[j] = *reinterpret_cast<bf16x8*>(&Ks[buf][(j * 16 + l15) * 64 + co]);
#pragma unroll
            for (int i = 0; i < 2; ++i)
#pragma unroll
                for (int j = 0; j < 4; ++j)
                    sacc[i][j] = __builtin_amdgcn_mfma_f32_16x16x32_bf16(ak[j], qreg[i][kk], sacc[i][j], 0, 0, 0);
        }

        // p = exp2(s); pack pairs (+0x8000 round) into wave-private P rows.
#pragma unroll
        for (int i = 0; i < 2; ++i) {
#pragma unroll
            for (int j = 0; j < 4; ++j) {
                float p0 = __builtin_amdgcn_exp2f(sacc[i][j][0]);
                float p1 = __builtin_amdgcn_exp2f(sacc[i][j][1]);
                float p2 = __builtin_amdgcn_exp2f(sacc[i][j][2]);
                float p3 = __builtin_amdgcn_exp2f(sacc[i][j][3]);
                union { float f; unsigned u; } a0{p0}, a1{p1}, a2{p2}, a3{p3};
                unsigned lo = __builtin_amdgcn_perm(a1.u + 0x8000u, a0.u + 0x8000u, 0x07060302u);
                unsigned hi = __builtin_amdgcn_perm(a3.u + 0x8000u, a2.u + 0x8000u, 0x07060302u);
                uint2 pk; pk.x = lo; pk.y = hi;
                *reinterpret_cast<uint2*>(&Pw[(i * 16 + l15) * LD + j * 16 + quad * 4]) = pk;
            }
        }

        // O += P·V ; l += P·ones (l lands in PV C-layout: row = q).
#pragma unroll
        for (int kk = 0; kk < 2; ++kk) {
            const int co = ((4 * kk + quad) ^ cb) * 8;
            bf16x8 ap[2];
#pragma unroll
            for (int i = 0; i < 2; ++i)
                ap[i] = *reinterpret_cast<bf16x8*>(&Pw[(i * 16 + l15) * LD + kk * 32 + quad * 8]);
#pragma unroll
            for (int i = 0; i < 2; ++i)
                lacc[i] = __builtin_amdgcn_mfma_f32_16x16x32_bf16(ap[i], ones, lacc[i], 0, 0, 0);
#pragma unroll
            for (int n = 0; n < 4; ++n) {
                bf16x8 bv = *reinterpret_cast<bf16x8*>(&Vs[buf][(n * 16 + l15) * 64 + co]);
#pragma unroll
                for (int i = 0; i < 2; ++i)
                    o[i][n] = __builtin_amdgcn_mfma_f32_16x16x32_bf16(ap[i], bv, o[i][n], 0, 0, 0);
            }
        }
        __syncthreads();  // K/V[buf] reads done; prefetch DMA (vmcnt) landed
    }

    // epilogue: rinv from lacc (already in o's row layout), store bf16 token layout
    const int b_ = bh >> 4, h = bh & 15;
#pragma unroll
    for (int i = 0; i < 2; ++i) {
        f32x4 rv;
#pragma unroll
        for (int r = 0; r < 4; ++r) rv[r] = 1.0f / lacc[i][r];
#pragma unroll
        for (int n = 0; n < 4; ++n)
#pragma unroll
            for (int r = 0; r < 4; ++r) {
                int s = q0 + wq + i * 16 + quad * 4 + r;
                int d = n * 16 + l15;
                Oa[(size_t)(b_ * 2048 + s) * 1024 + h * 64 + d] =
                    (unsigned short)f2bf(o[i][n][r] * rv[r]);
            }
    }
}

extern "C" void kernel_launch(void* const* d_in, const int* in_sizes, int n_in,
                              void* d_out, int out_size, void* d_ws, size_t ws_size,
                              hipStream_t stream) {
    const float* q  = (const float*)d_in[0];
    const float* k  = (const float*)d_in[1];
    const float* v  = (const float*)d_in[2];
    const float* Wq = (const float*)d_in[3];
    const float* bq = (const float*)d_in[4];
    const float* Wk = (const float*)d_in[5];
    const float* bk = (const float*)d_in[6];
    const float* Wv = (const float*)d_in[7];
    const float* bv = (const float*)d_in[8];
    const float* Wo = (const float*)d_in[9];
    const float* bo = (const float*)d_in[10];

    const size_t E = (size_t)8192 * 1024;
    const size_t WE = (size_t)1024 * 1024;
    // aliasing (sequential dependency chain): r0=q_bf->Kh ; r1=k_bf->Vt ; r2=v_bf->Ao ; r3=Qh
    unsigned short* r0 = (unsigned short*)d_ws;
    unsigned short* r1 = r0 + E;
    unsigned short* r2 = r1 + E;
    unsigned short* r3 = r2 + E;
    unsigned short* wqb = r3 + E;
    unsigned short* wkb = wqb + WE;
    unsigned short* wvb = wkb + WE;
    unsigned short* wob = wvb + WE;

    CvtArgs ca;
    ca.s[0] = q; ca.d[0] = r0;
    ca.s[1] = k; ca.d[1] = r1;
    ca.s[2] = v; ca.d[2] = r2;
    ca.s[3] = q; ca.d[3] = r0;  // unused (grid.y = 3)
    ca.n4 = (int)(E / 4);
    cvt_bf16<<<dim3(1024, 3), 256, 0, stream>>>(ca);

    CvtArgs cw;
    cw.s[0] = Wq; cw.d[0] = wqb;
    cw.s[1] = Wk; cw.d[1] = wkb;
    cw.s[2] = Wv; cw.d[2] = wvb;
    cw.s[3] = Wo; cw.d[3] = wob;
    cw.n4 = (int)(WE / 4);
    cvt_bf16<<<dim3(256, 4), 256, 0, stream>>>(cw);

    const float QSCALE = 0.125f * 1.44269504088896340736f;  // fold log2(e) for exp2

    QkvArgs ga;
    ga.A[0] = r0; ga.W[0] = wqb; ga.bias[0] = bq; ga.scale[0] = QSCALE; ga.out[0] = r3; ga.mode[0] = 1;
    ga.A[1] = r1; ga.W[1] = wkb; ga.bias[1] = bk; ga.scale[1] = 1.0f;   ga.out[1] = r0; ga.mode[1] = 1;
    ga.A[2] = r2; ga.W[2] = wvb; ga.bias[2] = bv; ga.scale[2] = 1.0f;   ga.out[2] = r1; ga.mode[2] = 2;
    gemm_qkv<<<dim3(8, 64, 3), 256, 0, stream>>>(ga);

    flash_attn<<<dim3(16, 64), 256, 0, stream>>>(r3, r0, r1, r2);  // Ao = r2
    gemm_wo<<<dim3(8, 64), 256, 0, stream>>>(r2, wob, bo, (float*)d_out);
}